// Round 7
// baseline (389.873 us; speedup 1.0000x reference)
//
#include <hip/hip_runtime.h>

// ---- problem constants ----
#define HWSZ 9216            // 96*96
#define CIN  256
#define NPER 8847360         // P*B*h*HW  (one output tensor, elements)
#define PSTRIDE 1474560      // B*h*HW (part stride)
#define IMG_STRIDE 2359296   // CIN*HW (p_fea batch stride)
#define BHW 92160            // h*HW (batch stride inside a part)

// ---- f32 weight workspace layout (element offsets) ----
#define OFF_WATT  18432
#define OFF_BATT  18492
#define OFF_WDPX  18498
#define OFF_BDP   18598
#define OFF_BPROJ 18608
#define OFF_WGATE 18668
#define OFF_BGATE 18788
#define OFF_WUPD  18794
#define OFF_BUPD  20594
#define WS_TOTAL  20654
// bf16 MFMA A-operand pack: ushort element offset (byte 82944, past f32 region)
#define A_OFF_U16 41472
#define A_ELEMS   20480      // 5 mtiles * 8 ksteps * 64 lanes * 8

typedef __attribute__((ext_vector_type(8))) short short8;
typedef __attribute__((ext_vector_type(4))) float f32x4;

// ---- LDS layout (float element offsets). Total 6776 f32 = 27104 B.
#define SS     66
#define L_S    0        // [70][66]  MFMA result (rows 0..9 dp-base, 10..69 proj)
#define L_DP1  4620     // [10][66]  dp of part 1
#define L_S1   5280     // [10][66]  sum_{q!=1} att_q * dp_q   (atomic)
#define L_SA   5940     // [66]      sum_{q!=1} att_q          (atomic)
#define L_ATT  6008     // [6][64]
#define L_GATE 6392     // [6][64]
#define L_TOT  6776

static __device__ __forceinline__ unsigned short f2b(float f) {
  union { float f; unsigned int i; } v; v.f = f;
  unsigned int u = v.i;
  return (unsigned short)((u + 0x7fffu + ((u >> 16) & 1u)) >> 16);  // RNE
}
static __device__ __forceinline__ float sigmoidf_(float x) {
  return 1.0f / (1.0f + __expf(-x));
}

// Gather f32 weights into d_ws AND pack the big [70x256] matrix (w_dp_f rows 0..9,
// w_proj rows 10..69) as bf16 MFMA A-fragments:
// A_pack[mtile][kstep][lane][j] = W[m=mtile*16+(lane&15)][k=kstep*32+((lane>>4)&3)*8+j]
__global__ void prep_weights(const float* __restrict__ w_att,
                             const float* __restrict__ b_att,
                             const float* __restrict__ w_dp_f,
                             const float* __restrict__ w_dp_x,
                             const float* __restrict__ b_dp,
                             const float* __restrict__ w_proj,
                             const float* __restrict__ b_proj,
                             const float* __restrict__ w_gate,
                             const float* __restrict__ b_gate,
                             const float* __restrict__ w_upd,
                             const float* __restrict__ b_upd,
                             float* __restrict__ ws)
{
  int i = blockIdx.x * 256 + threadIdx.x;
  if (i < A_ELEMS) {
    int j     = i & 7;
    int lane  = (i >> 3) & 63;
    int kstep = (i >> 9) & 7;
    int mtile = i >> 12;
    int m = mtile * 16 + (lane & 15);
    int k = kstep * 32 + ((lane >> 4) & 3) * 8 + j;
    float wv = (m < 10) ? w_dp_f[m * CIN + k]
             : (m < 70) ? w_proj[(m - 10) * CIN + k] : 0.f;
    ((unsigned short*)ws)[A_OFF_U16 + i] = f2b(wv);
  }
  if (i >= WS_TOTAL || i < OFF_WATT) return;
  float v;
  if      (i < OFF_BATT)  v = w_att [i - OFF_WATT ];
  else if (i < OFF_WDPX)  v = b_att [i - OFF_BATT ];
  else if (i < OFF_BDP)   v = w_dp_x[i - OFF_WDPX ];
  else if (i < OFF_BPROJ) v = b_dp  [i - OFF_BDP  ];
  else if (i < OFF_WGATE) v = b_proj[i - OFF_BPROJ];
  else if (i < OFF_BGATE) v = w_gate[i - OFF_WGATE];
  else if (i < OFF_WUPD)  v = b_gate[i - OFF_BGATE];
  else if (i < OFF_BUPD)  v = w_upd [i - OFF_WUPD ];
  else                    v = b_upd [i - OFF_BUPD ];
  ws[i] = v;
}

// ---- epilogue helpers: part p is WAVE-UNIFORM (p = wave, 6 waves = 6 parts).
// readfirstlane pins all weight/output bases to SGPRs. Round-4 lesson: a
// half-wave part index made weight access lane-divergent -> VGPR 180.

// prefetch + att/gate (no LDS dependence; xh streamed, never kept)
static __device__ __forceinline__ void prefetch_ag(
    int p, int px, size_t ebase,
    const float* __restrict__ xp, const float* __restrict__ xh,
    const float* __restrict__ ws, float* __restrict__ smem,
    float* __restrict__ xpv, float& att)
{
  const int pu = __builtin_amdgcn_readfirstlane(p);
  const float* xpb = xp + (size_t)pu * PSTRIDE + ebase;
  const float* xhb = xh + (size_t)(pu >= 4 ? 1 : 0) * PSTRIDE + ebase;
  float asum = ws[OFF_BATT + pu], gsum = ws[OFF_BGATE + pu];
#pragma unroll
  for (int ch = 0; ch < 10; ++ch)
    xpv[ch] = xpb[(size_t)ch * HWSZ];
#pragma unroll
  for (int ch = 0; ch < 10; ++ch) {
    float hv = xhb[(size_t)ch * HWSZ];
    asum = fmaf(ws[OFF_WATT  + pu * 10 + ch],      xpv[ch], asum);
    gsum = fmaf(ws[OFF_WGATE + pu * 20 + 10 + ch], xpv[ch], gsum);
    gsum = fmaf(ws[OFF_WGATE + pu * 20 + ch],      hv,      gsum);
  }
  att = sigmoidf_(asum);
  smem[L_ATT  + pu * 64 + px] = att;
  smem[L_GATE + pu * 64 + px] = sigmoidf_(gsum);
}

// e1: dp from S + xpv; part 1 -> dpL; others -> s1/sA atomics
static __device__ __forceinline__ void e1_body(
    int p, int px, const float* __restrict__ ws,
    float* __restrict__ smem, const float* __restrict__ xpv, float att)
{
#pragma unroll
  for (int ch = 0; ch < 10; ++ch) {
    float tv = smem[L_S + ch * SS + px] + ws[OFF_BDP + ch];
#pragma unroll
    for (int j = 0; j < 10; ++j)
      tv = fmaf(ws[OFF_WDPX + ch * 10 + j], xpv[j], tv);
    tv = fmaxf(tv, 0.f);
    if (p == 1) smem[L_DP1 + ch * SS + px] = tv;
    else        atomicAdd(&smem[L_S1 + ch * SS + px], att * tv);
  }
  if (p != 1) atomicAdd(&smem[L_SA + px], att);
}

// e2: xpp, xhp, update, stores
static __device__ __forceinline__ void e2_body(
    int p, int px, size_t ebase, const float* __restrict__ ws,
    const float* __restrict__ smem, const float* __restrict__ xpv,
    float* __restrict__ out)
{
  const int pu = __builtin_amdgcn_readfirstlane(p);
  float attp = smem[L_ATT + pu * 64 + px];
  float att1 = smem[L_ATT + 64 + px];
  float g    = smem[L_GATE + pu * 64 + px];
  float aa   = att1 * attp;
  float sa   = smem[L_SA + px];

  float* o0 = out + (size_t)pu * PSTRIDE + ebase;
  const float* wu = ws + OFF_WUPD + pu * 300;   // [10 out][30 in], SGPR base

  float u[10];
#pragma unroll
  for (int q = 0; q < 10; ++q) u[q] = ws[OFF_BUPD + pu * 10 + q];

#pragma unroll
  for (int ch = 0; ch < 10; ++ch) {
    float xpp;
    if (pu == 1)
      xpp = att1 * fmaf(sa, xpv[ch], smem[L_S1 + ch * SS + px]);
    else
      xpp = aa * (smem[L_DP1 + ch * SS + px] + xpv[ch]);
    float pr  = smem[L_S + (10 + pu * 10 + ch) * SS + px];
    float xhp = g * (pr + ws[OFF_BPROJ + pu * 10 + ch]);

    o0[(size_t)ch * HWSZ + NPER]             = xpp;
    o0[(size_t)ch * HWSZ + 2 * (size_t)NPER] = xhp;

#pragma unroll
    for (int q = 0; q < 10; ++q) {
      u[q] = fmaf(wu[q * 30 + ch],      xpv[ch], u[q]);
      u[q] = fmaf(wu[q * 30 + 10 + ch], xpp,     u[q]);
      u[q] = fmaf(wu[q * 30 + 20 + ch], xhp,     u[q]);
    }
  }
#pragma unroll
  for (int q = 0; q < 10; ++q)
    o0[(size_t)q * HWSZ] = xpv[q] + fmaxf(u[q], 0.f);
}

// grid = 2304 (=147456 px / 64), block = 384 (6 waves: wave = part).
// Waves 0-3: 4-deep-pipelined p_fea gather + MFMA (16 px each) -> S, then
//            prefetch their part's xp/xh + att/gate.
// Waves 4-5: zero s1/sA, prefetch parts 4/5 (runs UNDER waves 0-3's MFMA).
// barrier -> e1 (one part per wave, balanced) -> barrier -> e2.
// Round-5 lessons: 2-deep gather pipe left ~200 stall cycles per k-step
// (8 loads ~300cy latency vs ~90cy of MFMA+cvt cover); pass-B on waves 0-1
// serialized 50% extra epilogue work while waves 2-3 idled.
// Round-6 was an infra failure (container failed twice, no counters);
// this source is resubmitted unchanged after a bounds/race/barrier audit.
// Launch bounds: NO min-waves clause (rounds 1-3: forcing a VGPR budget makes
// the allocator demote whole arrays to scratch -> +450 MB RW traffic).
__global__ __launch_bounds__(384) void part_graph_main(
    const float* __restrict__ p_fea,
    const float* __restrict__ xp,
    const float* __restrict__ xh,
    const float* __restrict__ ws,
    float* __restrict__ out)
{
  __shared__ __align__(16) float smem[L_TOT];

  const int tid = threadIdx.x;
  const int b   = blockIdx.x / 144;
  const int s0  = (blockIdx.x % 144) * 64;

  const int lane = tid & 63, wv = tid >> 6;   // wv = 0..5 = part
  const int px = lane;
  const size_t ebase = (size_t)b * BHW + s0 + px;

  float xpv[10], att2;

  if (wv >= 4) {
    // ---- zero the atomic accumulators (s1 + sA contiguous: 726 floats) ----
    for (int i = tid - 256; i < 726; i += 128) smem[L_S1 + i] = 0.f;
    // ---- prefetch parts 4/5 while waves 0-3 run the MFMA phase ----
    prefetch_ag(wv, px, ebase, xp, xh, ws, smem, xpv, att2);
  } else {
    // ---- direct global gather of B-fragments fused with MFMA, 4-deep pipe --
    // D[70x16] = W[70x256] @ F[256x16] per wave (wave wv -> pixels wv*16..+15).
    const int l15 = lane & 15, quad = lane >> 4;
    const float* pf = p_fea + (size_t)b * IMG_STRIDE + s0 + wv * 16 + l15
                    + (size_t)quad * 8 * HWSZ;
    const short8* ap = (const short8*)((const unsigned short*)ws + A_OFF_U16);

    f32x4 acc[5];
#pragma unroll
    for (int mt = 0; mt < 5; ++mt) acc[mt] = (f32x4){0.f, 0.f, 0.f, 0.f};

    float t[4][8];   // 3 batches in flight (~24 outstanding loads)
#pragma unroll
    for (int pb = 0; pb < 3; ++pb)
#pragma unroll
      for (int j = 0; j < 8; ++j)
        t[pb][j] = pf[(size_t)(pb * 32 + j) * HWSZ];

#pragma unroll
    for (int ks = 0; ks < 8; ++ks) {
      if (ks < 5) {
#pragma unroll
        for (int j = 0; j < 8; ++j)
          t[(ks + 3) & 3][j] = pf[(size_t)((ks + 3) * 32 + j) * HWSZ];
      }
      short8 bf;
#pragma unroll
      for (int j = 0; j < 8; ++j) bf[j] = (short)f2b(t[ks & 3][j]);
#pragma unroll
      for (int mt = 0; mt < 5; ++mt)
        acc[mt] = __builtin_amdgcn_mfma_f32_16x16x32_bf16(
            ap[(mt * 8 + ks) * 64 + lane], bf, acc[mt], 0, 0, 0);
    }

    // ---- transpose acc -> S[m][px] (C/D: col=lane&15 -> px, row=quad*4+r) --
#pragma unroll
    for (int mt = 0; mt < 5; ++mt) {
#pragma unroll
      for (int r = 0; r < 4; ++r) {
        int m = mt * 16 + quad * 4 + r;
        if (m < 70) smem[L_S + m * SS + wv * 16 + l15] = acc[mt][r];
      }
    }

    // pin: don't hoist the epilogue prefetch over live acc[]
    __builtin_amdgcn_sched_barrier(0);

    prefetch_ag(wv, px, ebase, xp, xh, ws, smem, xpv, att2);
  }
  __syncthreads();

  // ---- epilogue 1: dp -> dp1 / s1,sA atomics (one part per wave) ----
  e1_body(wv, px, ws, smem, xpv, att2);
  __syncthreads();

  // ---- epilogue 2: xpp, xhp, update, stores ----
  e2_body(wv, px, ebase, ws, smem, xpv, out);
}

extern "C" void kernel_launch(void* const* d_in, const int* in_sizes, int n_in,
                              void* d_out, int out_size, void* d_ws, size_t ws_size,
                              hipStream_t stream) {
  const float* p_fea = (const float*)d_in[0];
  const float* xp    = (const float*)d_in[1];
  const float* xh    = (const float*)d_in[2];
  float* ws = (float*)d_ws;

  prep_weights<<<(WS_TOTAL + 255) / 256, 256, 0, stream>>>(
      (const float*)d_in[3],  (const float*)d_in[4],
      (const float*)d_in[5],  (const float*)d_in[6],
      (const float*)d_in[7],  (const float*)d_in[8],
      (const float*)d_in[9],  (const float*)d_in[10],
      (const float*)d_in[11], (const float*)d_in[12],
      (const float*)d_in[13], ws);

  part_graph_main<<<2304, 384, 0, stream>>>(
      p_fea, xp, xh, ws, (float*)d_out);
}